// Round 1
// baseline (4084.978 us; speedup 1.0000x reference)
//
#include <hip/hip_runtime.h>

#define TT 512
#define BB 64
#define II 512
#define LL 1024
#define NWG 64

typedef __bf16 bf16x8 __attribute__((ext_vector_type(8)));
typedef float f32x4 __attribute__((ext_vector_type(4)));

// ---------- workspace layout (bytes) ----------
// wsWi : Wi frag-ordered bf16 [8 bn][16 ks][8 nsub][64 lane][8e]  = 1 MiB
// wsWh : Wh frag-ordered bf16 [64 wg][32 ks][64 lane][8e]         = 2 MiB
// hbuf : ping-pong H frag-ordered bf16 2 x [4 mt][32 ks][64][8e]  = 256 KiB
// bar  : one uint barrier counter
#define WSWI_OFF 0u
#define WSWH_OFF (1u << 20)
#define HBUF_OFF (3u << 20)
#define BAR_OFF  ((3u << 20) + (1u << 18))

__device__ __forceinline__ unsigned short f2bf(float f) {
  unsigned int u = __builtin_bit_cast(unsigned int, f);
  u += 0x7fffu + ((u >> 16) & 1u);   // round-to-nearest-even (inputs finite)
  return (unsigned short)(u >> 16);
}

__device__ __forceinline__ bf16x8 ld_frag(const unsigned short* p) {
  return __builtin_bit_cast(bf16x8, *(const uint4*)p);
}

// ============================================================
// prep: fragment-order bf16 conversion of Wi, Wh, h0; zero bar.
// One slot = 8 consecutive k-elements (16B write).
// ============================================================
__global__ __launch_bounds__(256) void prep_kernel(
    const float* __restrict__ h0, const float* __restrict__ Wi,
    const float* __restrict__ Wh, unsigned short* __restrict__ wsWi,
    unsigned short* __restrict__ wsWh, unsigned short* __restrict__ hbuf,
    unsigned int* __restrict__ bar) {
  int idx = blockIdx.x * 256 + threadIdx.x;
  if (idx == 0) *bar = 0u;
  const float* src;
  unsigned short* dst;
  if (idx < 65536) {                       // Wi slots
    int ln = idx & 63, s = idx >> 6;
    int nsub = s & 7, s2 = s >> 3, ks = s2 & 15, bn = s2 >> 4;
    int n = bn * 128 + nsub * 16 + (ln & 15);
    int k = ks * 32 + (ln >> 4) * 8;
    src = Wi + (size_t)n * II + k;
    dst = wsWi + (size_t)idx * 8;
  } else if (idx < 196608) {               // Wh slots
    int o = idx - 65536;
    int ln = o & 63, s = o >> 6, ks = s & 31, wg = s >> 5;
    int col = wg * 16 + (ln & 15);
    int k = ks * 32 + (ln >> 4) * 8;
    src = Wh + (size_t)col * LL + k;
    dst = wsWh + (size_t)o * 8;
  } else if (idx < 204800) {               // h0 slots
    int o = idx - 196608;
    int ln = o & 63, s = o >> 6, ks = s & 31, mt = s >> 5;
    int b = mt * 16 + (ln & 15);
    int k = ks * 32 + (ln >> 4) * 8;
    src = h0 + (size_t)b * LL + k;
    dst = hbuf + (size_t)o * 8;
  } else {
    return;
  }
  float4 a0 = *(const float4*)src;
  float4 a1 = *(const float4*)(src + 4);
  uint4 p;
  p.x = f2bf(a0.x) | ((unsigned)f2bf(a0.y) << 16);
  p.y = f2bf(a0.z) | ((unsigned)f2bf(a0.w) << 16);
  p.z = f2bf(a1.x) | ((unsigned)f2bf(a1.y) << 16);
  p.w = f2bf(a1.z) | ((unsigned)f2bf(a1.w) << 16);
  *(uint4*)dst = p;
}

// ============================================================
// xi = x @ Wi^T + bi   -> written into d_out (reused as xi buffer)
// 128x128 tile, BK=32, 4 waves (2x2), mfma 16x16x32 bf16.
// A: fp32 global -> reg -> cvt -> frag-ordered LDS.
// B: pre-converted frag-ordered from ws.
// ============================================================
__global__ __launch_bounds__(256) void xi_gemm(
    const float* __restrict__ x, const float* __restrict__ bi,
    const unsigned short* __restrict__ wsWi, float* __restrict__ out) {
  __shared__ unsigned short As[8 * 64 * 8];  // [msub][lane][8e] 8 KiB
  __shared__ unsigned short Bs[8 * 64 * 8];  // [nsub][lane][8e] 8 KiB
  const int tid = threadIdx.x;
  const int ln = tid & 63;
  const int wv = tid >> 6;
  const int wm = wv >> 1, wn = wv & 1;
  const int bn = blockIdx.x;                 // 0..7
  const int Mbase = blockIdx.y * 128;
  const int Nbase = bn * 128;

  f32x4 acc[4][4] = {};

  for (int ks = 0; ks < 16; ++ks) {
    __syncthreads();
#pragma unroll
    for (int i = 0; i < 2; ++i) {
      int slot = tid + 256 * i;
      int msub = slot >> 6;
      int l2 = slot & 63;
      const float* src =
          x + (size_t)(Mbase + msub * 16 + (l2 & 15)) * II + ks * 32 + (l2 >> 4) * 8;
      float4 a0 = *(const float4*)src;
      float4 a1 = *(const float4*)(src + 4);
      uint4 p;
      p.x = f2bf(a0.x) | ((unsigned)f2bf(a0.y) << 16);
      p.y = f2bf(a0.z) | ((unsigned)f2bf(a0.w) << 16);
      p.z = f2bf(a1.x) | ((unsigned)f2bf(a1.y) << 16);
      p.w = f2bf(a1.z) | ((unsigned)f2bf(a1.w) << 16);
      *(uint4*)(As + slot * 8) = p;
      // B: contiguous copy from frag-ordered ws
      const uint4* bsrc = (const uint4*)(wsWi + (size_t)(bn * 16 + ks) * 4096) + slot;
      *(uint4*)(Bs + slot * 8) = *bsrc;
    }
    __syncthreads();
    bf16x8 af[4];
#pragma unroll
    for (int m = 0; m < 4; ++m)
      af[m] = ld_frag(As + ((wm * 4 + m) * 64 + ln) * 8);
#pragma unroll
    for (int n = 0; n < 4; ++n) {
      bf16x8 bf = ld_frag(Bs + ((wn * 4 + n) * 64 + ln) * 8);
#pragma unroll
      for (int m = 0; m < 4; ++m)
        acc[m][n] = __builtin_amdgcn_mfma_f32_16x16x32_bf16(af[m], bf, acc[m][n], 0, 0, 0);
    }
  }
#pragma unroll
  for (int n = 0; n < 4; ++n) {
    int col = Nbase + wn * 64 + n * 16 + (ln & 15);
    float bv = bi[col];
#pragma unroll
    for (int m = 0; m < 4; ++m) {
      int row0 = Mbase + wm * 64 + m * 16 + (ln >> 4) * 4;
#pragma unroll
      for (int r = 0; r < 4; ++r)
        out[(size_t)(row0 + r) * LL + col] = acc[m][n][r] + bv;
    }
  }
}

// ============================================================
// Persistent cooperative scan: 64 WGs x 512 thr, WG owns 16 cols.
// Wh slice LDS-resident (frag order).  H ping-pong in ws (frag order).
// 8 waves split K (128 each), LDS reduce, tanh, store, grid barrier.
// ============================================================
__global__ __launch_bounds__(512) void scan_kernel(
    const unsigned short* __restrict__ wsWh, float* __restrict__ out,
    unsigned short* __restrict__ hbuf, unsigned int* __restrict__ bar) {
  __shared__ unsigned short Bfrag[32 * 64 * 8];  // 32 KiB: [ks][lane][8e]
  __shared__ f32x4 red[8][4][64];                // 32 KiB
  const int tid = threadIdx.x;
  const int ln = tid & 63;
  const int wv = tid >> 6;   // 0..7
  const int wg = blockIdx.x; // 0..63

  { // load this WG's Wh fragment slice once
    const uint4* src = (const uint4*)(wsWh + (size_t)wg * 32 * 64 * 8);
    uint4* dst = (uint4*)Bfrag;
#pragma unroll
    for (int i = 0; i < 4; ++i) dst[tid + 512 * i] = src[tid + 512 * i];
  }
  __syncthreads();

  for (int t = 0; t < TT; ++t) {
    const unsigned short* hcur = hbuf + (size_t)(t & 1) * 65536;
    unsigned short* hnext = hbuf + (size_t)((t + 1) & 1) * 65536;

    f32x4 acc[4] = {};
#pragma unroll
    for (int kk = 0; kk < 4; ++kk) {
      int ks = wv * 4 + kk;
      bf16x8 bf = ld_frag(Bfrag + (ks * 64 + ln) * 8);
#pragma unroll
      for (int m = 0; m < 4; ++m) {
        bf16x8 af = ld_frag(hcur + (size_t)((m * 32 + ks) * 64 + ln) * 8);
        acc[m] = __builtin_amdgcn_mfma_f32_16x16x32_bf16(af, bf, acc[m], 0, 0, 0);
      }
    }
#pragma unroll
    for (int m = 0; m < 4; ++m) red[wv][m][ln] = acc[m];
    __syncthreads();

    if (wv < 4) {
      const int m = wv;
      f32x4 s = red[0][m][ln];
#pragma unroll
      for (int kh = 1; kh < 8; ++kh) s += red[kh][m][ln];
      const int col = wg * 16 + (ln & 15);
      const int lanep_hi = ((2 * wg + ((ln & 15) >> 3)) & 3) * 16;
      const int ksp = wg >> 1;
      float* obase = out + (size_t)t * (BB * LL) + col;
#pragma unroll
      for (int r = 0; r < 4; ++r) {
        int row = m * 16 + (ln >> 4) * 4 + r;
        float z = s[r] + obase[(size_t)row * LL];
        float h = tanhf(z);
        obase[(size_t)row * LL] = h;
        int lanep = lanep_hi + (row & 15);
        hnext[(size_t)((m * 32 + ksp) * 64 + lanep) * 8 + (ln & 7)] = f2bf(h);
      }
    }

    // ---- grid barrier (monotonic counter) ----
    __syncthreads();
    if (tid == 0) {
      __builtin_amdgcn_fence(__ATOMIC_RELEASE, "agent");
      __hip_atomic_fetch_add(bar, 1u, __ATOMIC_RELAXED, __HIP_MEMORY_SCOPE_AGENT);
      unsigned int tgt = (unsigned int)NWG * (unsigned int)(t + 1);
      while (__hip_atomic_load(bar, __ATOMIC_RELAXED, __HIP_MEMORY_SCOPE_AGENT) < tgt) {
        __builtin_amdgcn_s_sleep(2);
      }
      __builtin_amdgcn_fence(__ATOMIC_ACQUIRE, "agent");
    }
    __syncthreads();
  }
}

extern "C" void kernel_launch(void* const* d_in, const int* in_sizes, int n_in,
                              void* d_out, int out_size, void* d_ws, size_t ws_size,
                              hipStream_t stream) {
  const float* x  = (const float*)d_in[0];
  const float* h0 = (const float*)d_in[1];
  const float* Wi = (const float*)d_in[2];
  const float* bi = (const float*)d_in[3];
  const float* Wh = (const float*)d_in[4];
  float* out = (float*)d_out;
  char* ws = (char*)d_ws;
  unsigned short* wsWi = (unsigned short*)(ws + WSWI_OFF);
  unsigned short* wsWh = (unsigned short*)(ws + WSWH_OFF);
  unsigned short* hbuf = (unsigned short*)(ws + HBUF_OFF);
  unsigned int* bar = (unsigned int*)(ws + BAR_OFF);

  prep_kernel<<<800, 256, 0, stream>>>(h0, Wi, Wh, wsWi, wsWh, hbuf, bar);
  xi_gemm<<<dim3(8, 256), 256, 0, stream>>>(x, bi, wsWi, out);
  void* args[] = {(void*)&wsWh, (void*)&out, (void*)&hbuf, (void*)&bar};
  hipLaunchCooperativeKernel(reinterpret_cast<void*>(scan_kernel), dim3(NWG),
                             dim3(512), args, 0, stream);
}